// Round 5
// baseline (240.356 us; speedup 1.0000x reference)
//
#include <hip/hip_runtime.h>
#include <stdint.h>

typedef __attribute__((ext_vector_type(4))) float  f32x4;
typedef __attribute__((ext_vector_type(8))) short  s16x8;
typedef __attribute__((ext_vector_type(4))) short  s16x4;

__device__ __forceinline__ unsigned short f2bf(float x) {
  union { float f; unsigned int u; } a; a.f = x;
  unsigned int lsb = (a.u >> 16) & 1u;
  a.u += 0x7fffu + lsb;                    // round-to-nearest-even
  return (unsigned short)(a.u >> 16);
}
__device__ __forceinline__ float bf2f(unsigned short h) {
  union { unsigned int u; float f; } a; a.u = ((unsigned int)h) << 16; return a.f;
}

// async global->LDS, 16B per lane. LDS dest must be wave-uniform base (+lane*16).
__device__ __forceinline__ void gload_lds16(const void* g, void* s) {
  __builtin_amdgcn_global_load_lds(
      (__attribute__((address_space(1))) void*)g,
      (__attribute__((address_space(3))) void*)s, 16, 0, 0);
}

// Bank-conflict swizzle for [row][32-bf16] LDS tiles (64-B rows, 4 chunks of
// 16 B). chunk' = chunk ^ ((row>>1)&3): 8-way -> 2-way (free). For
// global_load_lds-staged tiles, LDS stays linear and the XOR is applied to
// the global source column (same-row permutation -> coalescing preserved).

// ---------------- K2: f32 -> bf16 (hi only) ----------------
__global__ __launch_bounds__(256) void k_convert_hi(
    const float* __restrict__ in, unsigned short* __restrict__ out, int n4) {
  int i = blockIdx.x * 256 + threadIdx.x;
  if (i < n4) {
    f32x4 v = ((const f32x4*)in)[i];
    s16x4 h;
#pragma unroll
    for (int j = 0; j < 4; j++) h[j] = (short)f2bf(v[j]);
    ((s16x4*)out)[i] = h;
  }
}

// ---------------- K3: f32 TN gemm: C[m][n] = sum_k A[m][k]*B[n][k] + bias[n] ----------------
__global__ __launch_bounds__(256) void k_gemm_f32_tn(
    const float* __restrict__ A, const float* __restrict__ Bm,
    const float* __restrict__ bias, float* __restrict__ C,
    int M, int N, int K) {
  __shared__ float As[32][33], Bs[32][33];
  int tid = threadIdx.x;
  int bm = blockIdx.x * 32, bn = blockIdx.y * 32;
  int tr = tid & 31, tq = tid >> 5;
  float acc[4] = {0.f, 0.f, 0.f, 0.f};
  for (int k0 = 0; k0 < K; k0 += 32) {
#pragma unroll
    for (int i = 0; i < 4; i++) {
      int idx = tid + i * 256;
      int r = idx >> 5, c = idx & 31;
      As[r][c] = A[(size_t)(bm + r) * K + k0 + c];
      Bs[r][c] = Bm[(size_t)(bn + r) * K + k0 + c];
    }
    __syncthreads();
#pragma unroll
    for (int kk = 0; kk < 32; kk++) {
      float b = Bs[tr][kk];
#pragma unroll
      for (int i = 0; i < 4; i++) acc[i] += As[tq * 4 + i][kk] * b;
    }
    __syncthreads();
  }
#pragma unroll
  for (int i = 0; i < 4; i++)
    C[(size_t)(bm + tq * 4 + i) * N + bn + tr] = acc[i] + bias[bn + tr];
}

// ---------------- K4: f32 NN gemm + bf16 hi/lo split output ----------------
__global__ __launch_bounds__(256) void k_gemm_f32_nn_split(
    const float* __restrict__ A, const float* __restrict__ Bm,
    unsigned short* __restrict__ Chi, unsigned short* __restrict__ Clo,
    int M, int N, int K) {
  __shared__ float As[32][33], Bs[32][33];
  int tid = threadIdx.x;
  int bm = blockIdx.x * 32, bn = blockIdx.y * 32;
  int tr = tid & 31, tq = tid >> 5;
  float acc[4] = {0.f, 0.f, 0.f, 0.f};
  for (int k0 = 0; k0 < K; k0 += 32) {
#pragma unroll
    for (int i = 0; i < 4; i++) {
      int idx = tid + i * 256;
      int r = idx >> 5, c = idx & 31;
      As[r][c] = A[(size_t)(bm + r) * K + k0 + c];
      Bs[r][c] = Bm[(size_t)(k0 + r) * N + bn + c];
    }
    __syncthreads();
#pragma unroll
    for (int kk = 0; kk < 32; kk++) {
      float b = Bs[kk][tr];
#pragma unroll
      for (int i = 0; i < 4; i++) acc[i] += As[tq * 4 + i][kk] * b;
    }
    __syncthreads();
  }
#pragma unroll
  for (int i = 0; i < 4; i++) {
    float q = acc[i];
    unsigned short hb = f2bf(q);
    size_t o = (size_t)(bm + tq * 4 + i) * N + bn + tr;
    Chi[o] = hb;
    Clo[o] = f2bf(q - bf2f(hb));
  }
}

// ---------------- K6: 3-pass split-bf16 TN gemm -> score partials ----------------
// A = QW (bf16 hi/lo, 128 x 1024). B = img f32, split hi/lo in-register.
// Grid: 1024 blocks = 512 N-tiles (64 wide) x 2 K-halves. LDS tiles swizzled.
__global__ __launch_bounds__(256, 4) void k_gemm_scores(
    const unsigned short* __restrict__ Ah, const unsigned short* __restrict__ Al,
    const float* __restrict__ img, float* __restrict__ Sp) {
  __shared__ unsigned short Ahs[4096], Als[4096];   // [128][32]
  __shared__ unsigned short Bhs[2048], Bls[2048];   // [64][32]
  int tid = threadIdx.x, l = tid & 63, w = tid >> 6;
  int wm = w >> 1, wn = w & 1;              // 2 x 2 wave grid over 128x64 tile
  int bid = blockIdx.x;
  int xcd = bid & 7, local = bid >> 3;      // local 0..127
  int ks = local & 1;
  int bn = (xcd * 64 + (local >> 1)) * 64;
  int kbase = ks * 512;
  float* S = Sp + (size_t)ks * 4194304;
  int lr = l & 15, lk8 = l >> 4;            // frag chunk index 0..3
  int sF = (lr >> 1) & 3;                   // frag-read swizzle
  int brow = tid >> 2, bcol8 = tid & 3;     // B staging: row, chunk
  int bswz = ((tid & 3) ^ ((tid >> 3) & 3));  // swizzled chunk (both A-src & B-dst)
  f32x4 acc[4][2] = {};
  for (int kk0 = 0; kk0 < 512; kk0 += 32) {
    int k0 = kbase + kk0;
    // A tiles: async gload, LDS linear, source column pre-swizzled
#pragma unroll
    for (int rnd = 0; rnd < 2; rnd++) {
      int row = rnd * 64 + (tid >> 2);
      size_t off = (size_t)row * 1024 + k0 + bswz * 8;
      gload_lds16(Ah + off, &Ahs[rnd * 2048 + w * 512]);
      gload_lds16(Al + off, &Als[rnd * 2048 + w * 512]);
    }
    // B tile: reg-stage f32 -> hi/lo bf16, swizzled ds_write
    {
      const float* g = img + (size_t)(bn + brow) * 1024 + k0 + bcol8 * 8;
      f32x4 v0 = *(const f32x4*)g;
      f32x4 v1 = *(const f32x4*)(g + 4);
      s16x8 h, lw;
#pragma unroll
      for (int j = 0; j < 4; j++) {
        unsigned short hb = f2bf(v0[j]);
        h[j] = (short)hb; lw[j] = (short)f2bf(v0[j] - bf2f(hb));
        unsigned short hb1 = f2bf(v1[j]);
        h[j + 4] = (short)hb1; lw[j + 4] = (short)f2bf(v1[j] - bf2f(hb1));
      }
      int byte = brow * 64 + (bswz << 4);
      *(s16x8*)((char*)Bhs + byte) = h;
      *(s16x8*)((char*)Bls + byte) = lw;
    }
    __syncthreads();
    s16x8 ah[4], al4[4], bh[2], bl[2];
#pragma unroll
    for (int i = 0; i < 4; i++) {
      int byte = (wm * 64 + i * 16 + lr) * 64 + ((lk8 ^ sF) << 4);
      ah[i] = *(const s16x8*)((const char*)Ahs + byte);
      al4[i] = *(const s16x8*)((const char*)Als + byte);
    }
#pragma unroll
    for (int j = 0; j < 2; j++) {
      int byte = (wn * 32 + j * 16 + lr) * 64 + ((lk8 ^ sF) << 4);
      bh[j] = *(const s16x8*)((const char*)Bhs + byte);
      bl[j] = *(const s16x8*)((const char*)Bls + byte);
    }
#pragma unroll
    for (int i = 0; i < 4; i++)
#pragma unroll
      for (int j = 0; j < 2; j++) {
        acc[i][j] = __builtin_amdgcn_mfma_f32_16x16x32_bf16(ah[i], bh[j], acc[i][j], 0, 0, 0);
        acc[i][j] = __builtin_amdgcn_mfma_f32_16x16x32_bf16(ah[i], bl[j], acc[i][j], 0, 0, 0);
        acc[i][j] = __builtin_amdgcn_mfma_f32_16x16x32_bf16(al4[i], bh[j], acc[i][j], 0, 0, 0);
      }
    __syncthreads();
  }
  int rh = (l >> 4) * 4;
#pragma unroll
  for (int i = 0; i < 4; i++)
#pragma unroll
    for (int q = 0; q < 4; q++) {
      int gm = wm * 64 + i * 16 + rh + q;
#pragma unroll
      for (int j = 0; j < 2; j++) {
        int gn = bn + wn * 32 + j * 16 + lr;
        S[(size_t)gm * 32768 + gn] = acc[i][j][q];
      }
    }
}

// ---------------- K9: fused softmax + ctx ----------------
// Per block (b, d0): softmax of batch b from score partials -> P_lds (bf16,
// swizzled), then ctx[b][l][d0:d0+128] = P @ img[b] via transpose-staged B.
__global__ __launch_bounds__(256, 2) void k_ctx_fused(
    const float* __restrict__ Sp, const float* __restrict__ img,
    unsigned short* __restrict__ Cp) {
  __shared__ unsigned short P[32768];   // [128 l][256 r] bf16, 512-B rows, chunk^(row&7)
  __shared__ unsigned short Bs[4096];   // imgT [128 d][32 r], 64-B rows, chunk^((d>>1)&3)
  int tid = threadIdx.x, l = tid & 63, w = tid >> 6;
  int wm = w >> 1, wn = w & 1;
  int rid = blockIdx.x;
  int xcd = rid & 7, lid = rid >> 3;
  int b = xcd * 16 + (lid >> 3);
  int d0 = (lid & 7) * 128;
  // ---- phase 0: softmax for batch b (redundant per d0-block, L2-fed) ----
  {
    const float* S0 = Sp + (size_t)b * 256;
    const float* S1 = S0 + 4194304;
#pragma unroll 1
    for (int p8 = 0; p8 < 4; ++p8) {
      int rbase = w * 32 + p8 * 8;
      f32x4 xa[8], xb[8];
#pragma unroll
      for (int i = 0; i < 8; i++)
        xa[i] = ((const f32x4*)(S0 + (size_t)(rbase + i) * 32768))[l];
#pragma unroll
      for (int i = 0; i < 8; i++)
        xb[i] = ((const f32x4*)(S1 + (size_t)(rbase + i) * 32768))[l];
#pragma unroll
      for (int i = 0; i < 8; i++) {
        int row = rbase + i;
        f32x4 x;
#pragma unroll
        for (int j = 0; j < 4; j++) x[j] = xa[i][j] + xb[i][j];
        float m = fmaxf(fmaxf(x[0], x[1]), fmaxf(x[2], x[3]));
#pragma unroll
        for (int s = 1; s < 64; s <<= 1) m = fmaxf(m, __shfl_xor(m, s, 64));
        f32x4 e;
        float sum = 0.f;
#pragma unroll
        for (int j = 0; j < 4; j++) { e[j] = __expf(x[j] - m); sum += e[j]; }
#pragma unroll
        for (int s = 1; s < 64; s <<= 1) sum += __shfl_xor(sum, s, 64);
        float sc = 0.03125f / sum;
        s16x4 o;
#pragma unroll
        for (int j = 0; j < 4; j++) o[j] = (short)f2bf(e[j] * sc);
        int byte = row * 512 + ((((l >> 1) ^ (row & 7)) << 4)) + (l & 1) * 8;
        *(s16x4*)((char*)P + byte) = o;
      }
    }
  }
  // ---- phase 1: ctx = P @ img_b (TN over r), B transpose-staged ----
  int lr = l & 15, lk8 = l >> 4;
  int u = tid & 15, dc = tid >> 4;
  int sP = lr & 7;                 // P-row swizzle (row&7 == lr&7 for frag rows)
  int sF = (lr >> 1) & 3;          // Bs frag-read swizzle
  f32x4 acc[4][4] = {};
  for (int k0 = 0; k0 < 256; k0 += 32) {
    // B: transpose-stage img[b][k0+r][d0+d] f32 -> bf16 pairs -> Bs[d][r]
    {
      const float* gsrc = img + ((size_t)(b * 256 + k0 + 2 * u)) * 1024 + d0 + dc * 8;
      f32x4 a0 = *(const f32x4*)gsrc;
      f32x4 a1 = *(const f32x4*)(gsrc + 4);
      f32x4 b0 = *(const f32x4*)(gsrc + 1024);
      f32x4 b1 = *(const f32x4*)(gsrc + 1028);
#pragma unroll
      for (int j = 0; j < 8; j++) {
        float x0 = (j < 4) ? a0[j & 3] : a1[j & 3];
        float x1 = (j < 4) ? b0[j & 3] : b1[j & 3];
        int d = dc * 8 + j;
        unsigned int w32 = (unsigned int)f2bf(x0) | ((unsigned int)f2bf(x1) << 16);
        int byte = d * 64 + ((4 * u) ^ (((d >> 1) & 3) << 4));
        *(unsigned int*)((char*)Bs + byte) = w32;
      }
    }
    __syncthreads();
    s16x8 af[4], bf[4];
    int chunkA = (k0 >> 3) | lk8;
#pragma unroll
    for (int i = 0; i < 4; i++) {
      int row = wm * 64 + i * 16 + lr;
      int byte = row * 512 + ((chunkA ^ sP) << 4);
      af[i] = *(const s16x8*)((const char*)P + byte);
    }
#pragma unroll
    for (int j = 0; j < 4; j++) {
      int n = wn * 64 + j * 16 + lr;
      int byte = n * 64 + ((lk8 ^ sF) << 4);
      bf[j] = *(const s16x8*)((const char*)Bs + byte);
    }
#pragma unroll
    for (int i = 0; i < 4; i++)
#pragma unroll
      for (int j = 0; j < 4; j++)
        acc[i][j] = __builtin_amdgcn_mfma_f32_16x16x32_bf16(af[i], bf[j], acc[i][j], 0, 0, 0);
    __syncthreads();
  }
  int rh = (l >> 4) * 4;
#pragma unroll
  for (int i = 0; i < 4; i++)
#pragma unroll
    for (int q = 0; q < 4; q++) {
      int gm = wm * 64 + i * 16 + rh + q;
#pragma unroll
      for (int j = 0; j < 4; j++) {
        int gn = wn * 64 + j * 16 + lr;
        Cp[((size_t)b * 128 + gm) * 1024 + d0 + gn] = f2bf(acc[i][j][q]);
      }
    }
}

// ---------------- K10: out[m][n] = sum_k ctx[m][k]*Wv[n][k] + bv[n]/32 ----------------
// M=16384, N=1024, K=1024. TN, swizzled LDS, XCD-grouped.
__global__ __launch_bounds__(256, 3) void k_gemm_out(
    const unsigned short* __restrict__ A, const unsigned short* __restrict__ Bm,
    const float* __restrict__ bv, float* __restrict__ Out) {
  __shared__ unsigned short As[4096], Bs[4096];
  int tid = threadIdx.x, l = tid & 63, w = tid >> 6;
  int wm = w >> 1, wn = w & 1;
  int rid = blockIdx.x;
  int xcd = rid & 7, lid = rid >> 3;
  int bm = (xcd * 16 + (lid >> 3)) * 128;
  int bn = (lid & 7) * 128;
  int lr = l & 15, lk8 = l >> 4;
  int sF = (lr >> 1) & 3;
  int swz = ((tid & 3) ^ ((tid >> 3) & 3));   // source-col swizzle for staging
  f32x4 acc[4][4] = {};
  for (int k0 = 0; k0 < 1024; k0 += 32) {
#pragma unroll
    for (int rnd = 0; rnd < 2; rnd++) {
      int row = rnd * 64 + (tid >> 2);
      int lbase = rnd * 2048 + w * 512;
      gload_lds16(A + (size_t)(bm + row) * 1024 + k0 + swz * 8, &As[lbase]);
      gload_lds16(Bm + (size_t)(bn + row) * 1024 + k0 + swz * 8, &Bs[lbase]);
    }
    __syncthreads();
    s16x8 af[4], bf[4];
#pragma unroll
    for (int i = 0; i < 4; i++) {
      int byte = (wm * 64 + i * 16 + lr) * 64 + ((lk8 ^ sF) << 4);
      af[i] = *(const s16x8*)((const char*)As + byte);
    }
#pragma unroll
    for (int i = 0; i < 4; i++) {
      int byte = (wn * 64 + i * 16 + lr) * 64 + ((lk8 ^ sF) << 4);
      bf[i] = *(const s16x8*)((const char*)Bs + byte);
    }
#pragma unroll
    for (int i = 0; i < 4; i++)
#pragma unroll
      for (int j = 0; j < 4; j++)
        acc[i][j] = __builtin_amdgcn_mfma_f32_16x16x32_bf16(af[i], bf[j], acc[i][j], 0, 0, 0);
    __syncthreads();
  }
  int rh = (l >> 4) * 4;
#pragma unroll
  for (int i = 0; i < 4; i++)
#pragma unroll
    for (int q = 0; q < 4; q++) {
      int gm = bm + wm * 64 + i * 16 + rh + q;
#pragma unroll
      for (int j = 0; j < 4; j++) {
        int gn = bn + wn * 64 + j * 16 + lr;
        Out[(size_t)gm * 1024 + gn] = acc[i][j][q] + 0.03125f * bv[gn];
      }
    }
}

extern "C" void kernel_launch(void* const* d_in, const int* in_sizes, int n_in,
                              void* d_out, int out_size, void* d_ws, size_t ws_size,
                              hipStream_t stream) {
  const float* cap = (const float*)d_in[0];
  const float* img = (const float*)d_in[1];
  const float* Wq  = (const float*)d_in[2];
  const float* bq  = (const float*)d_in[3];
  const float* Wk  = (const float*)d_in[4];
  // d_in[5] = bk: constant across r -> cancels in softmax. Unused.
  const float* Wv  = (const float*)d_in[6];
  const float* bv  = (const float*)d_in[7];
  float* out = (float*)d_out;

  char* ws = (char*)d_ws;
  if (ws_size < 70254592ull) return;  // fail loudly (output stays poisoned)
  float*          scores = (float*)(ws);                     // 32 MB (2 K-halves)
  unsigned short* ctx    = (unsigned short*)(ws + 33554432); // 32 MB
  float*          Qb     = (float*)(ws + 67108864);          // 512 KB
  unsigned short* QWh    = (unsigned short*)(ws + 67633152); // 256 KB
  unsigned short* QWl    = (unsigned short*)(ws + 67895296); // 256 KB
  unsigned short* Wvh    = (unsigned short*)(ws + 68157440); //   2 MB

  k_convert_hi<<<1024, 256, 0, stream>>>(Wv, Wvh, 1048576 / 4);
  // Q = cap @ Wq^T + bq  (f32)
  k_gemm_f32_tn<<<dim3(4, 32), 256, 0, stream>>>(cap, Wq, bq, Qb, 128, 1024, 1024);
  // QW = Q @ Wk  (f32 -> bf16 hi/lo)
  k_gemm_f32_nn_split<<<dim3(4, 32), 256, 0, stream>>>(Qb, Wk, QWh, QWl, 128, 1024, 1024);
  // score partials = QW @ img^T  (3-pass split bf16, img split in-register)
  k_gemm_scores<<<1024, 256, 0, stream>>>(QWh, QWl, img, scores);
  // ctx[b][l][d] = softmax(scores)/32 @ img[b]  (fused, bf16)
  k_ctx_fused<<<1024, 256, 0, stream>>>(scores, img, ctx);
  // out = ctx @ Wv^T + bv/32
  k_gemm_out<<<1024, 256, 0, stream>>>(ctx, Wvh, bv, out);
}

// Round 6
// 233.622 us; speedup vs baseline: 1.0288x; 1.0288x over previous
//
#include <hip/hip_runtime.h>
#include <stdint.h>

typedef __attribute__((ext_vector_type(4))) float  f32x4;
typedef __attribute__((ext_vector_type(8))) short  s16x8;
typedef __attribute__((ext_vector_type(4))) short  s16x4;

__device__ __forceinline__ unsigned short f2bf(float x) {
  union { float f; unsigned int u; } a; a.f = x;
  unsigned int lsb = (a.u >> 16) & 1u;
  a.u += 0x7fffu + lsb;                    // round-to-nearest-even
  return (unsigned short)(a.u >> 16);
}
__device__ __forceinline__ float bf2f(unsigned short h) {
  union { unsigned int u; float f; } a; a.u = ((unsigned int)h) << 16; return a.f;
}

// async global->LDS, 16B per lane. LDS dest must be wave-uniform base (+lane*16).
__device__ __forceinline__ void gload_lds16(const void* g, void* s) {
  __builtin_amdgcn_global_load_lds(
      (__attribute__((address_space(1))) void*)g,
      (__attribute__((address_space(3))) void*)s, 16, 0, 0);
}

// Bank-conflict swizzle for [row][32-bf16] LDS tiles (64-B rows, 4 chunks of
// 16 B). chunk' = chunk ^ ((row>>1)&3). For global_load_lds-staged tiles the
// LDS stays linear and the XOR is applied to the global source column.

// ---------------- K2: f32 -> bf16 (hi only) ----------------
__global__ __launch_bounds__(256) void k_convert_hi(
    const float* __restrict__ in, unsigned short* __restrict__ out, int n4) {
  int i = blockIdx.x * 256 + threadIdx.x;
  if (i < n4) {
    f32x4 v = ((const f32x4*)in)[i];
    s16x4 h;
#pragma unroll
    for (int j = 0; j < 4; j++) h[j] = (short)f2bf(v[j]);
    ((s16x4*)out)[i] = h;
  }
}

// ---------------- K3: f32 TN gemm: C[m][n] = sum_k A[m][k]*B[n][k] + bias[n] ----------------
__global__ __launch_bounds__(256) void k_gemm_f32_tn(
    const float* __restrict__ A, const float* __restrict__ Bm,
    const float* __restrict__ bias, float* __restrict__ C,
    int M, int N, int K) {
  __shared__ float As[32][33], Bs[32][33];
  int tid = threadIdx.x;
  int bm = blockIdx.x * 32, bn = blockIdx.y * 32;
  int tr = tid & 31, tq = tid >> 5;
  float acc[4] = {0.f, 0.f, 0.f, 0.f};
  for (int k0 = 0; k0 < K; k0 += 32) {
#pragma unroll
    for (int i = 0; i < 4; i++) {
      int idx = tid + i * 256;
      int r = idx >> 5, c = idx & 31;
      As[r][c] = A[(size_t)(bm + r) * K + k0 + c];
      Bs[r][c] = Bm[(size_t)(bn + r) * K + k0 + c];
    }
    __syncthreads();
#pragma unroll
    for (int kk = 0; kk < 32; kk++) {
      float b = Bs[tr][kk];
#pragma unroll
      for (int i = 0; i < 4; i++) acc[i] += As[tq * 4 + i][kk] * b;
    }
    __syncthreads();
  }
#pragma unroll
  for (int i = 0; i < 4; i++)
    C[(size_t)(bm + tq * 4 + i) * N + bn + tr] = acc[i] + bias[bn + tr];
}

// ---------------- K4: f32 NN gemm + bf16 hi/lo split output ----------------
__global__ __launch_bounds__(256) void k_gemm_f32_nn_split(
    const float* __restrict__ A, const float* __restrict__ Bm,
    unsigned short* __restrict__ Chi, unsigned short* __restrict__ Clo,
    int M, int N, int K) {
  __shared__ float As[32][33], Bs[32][33];
  int tid = threadIdx.x;
  int bm = blockIdx.x * 32, bn = blockIdx.y * 32;
  int tr = tid & 31, tq = tid >> 5;
  float acc[4] = {0.f, 0.f, 0.f, 0.f};
  for (int k0 = 0; k0 < K; k0 += 32) {
#pragma unroll
    for (int i = 0; i < 4; i++) {
      int idx = tid + i * 256;
      int r = idx >> 5, c = idx & 31;
      As[r][c] = A[(size_t)(bm + r) * K + k0 + c];
      Bs[r][c] = Bm[(size_t)(k0 + r) * N + bn + c];
    }
    __syncthreads();
#pragma unroll
    for (int kk = 0; kk < 32; kk++) {
      float b = Bs[kk][tr];
#pragma unroll
      for (int i = 0; i < 4; i++) acc[i] += As[tq * 4 + i][kk] * b;
    }
    __syncthreads();
  }
#pragma unroll
  for (int i = 0; i < 4; i++) {
    float q = acc[i];
    unsigned short hb = f2bf(q);
    size_t o = (size_t)(bm + tq * 4 + i) * N + bn + tr;
    Chi[o] = hb;
    Clo[o] = f2bf(q - bf2f(hb));
  }
}

// ---------------- K6: 3-pass split-bf16 TN gemm -> score partials ----------------
// A = QW (bf16 hi/lo, 128 x 1024). B = img f32, split hi/lo in-register.
// BK=64 via two 32-wide subtiles (keeps 64-B-row swizzled layout).
// Grid: 1024 blocks = 512 N-tiles (64 wide) x 2 K-halves. 48 KB LDS -> 3/CU.
__global__ __launch_bounds__(256, 3) void k_gemm_scores(
    const unsigned short* __restrict__ Ah, const unsigned short* __restrict__ Al,
    const float* __restrict__ img, float* __restrict__ Sp) {
  __shared__ unsigned short Ahs[8192], Als[8192];   // 2 subtiles x [128][32]
  __shared__ unsigned short Bhs[4096], Bls[4096];   // 2 subtiles x [64][32]
  int tid = threadIdx.x, l = tid & 63, w = tid >> 6;
  int wm = w >> 1, wn = w & 1;              // 2 x 2 wave grid over 128x64 tile
  int bid = blockIdx.x;
  int xcd = bid & 7, local = bid >> 3;      // local 0..127
  int ks = local & 1;
  int bn = (xcd * 64 + (local >> 1)) * 64;
  int kbase = ks * 512;
  float* S = Sp + (size_t)ks * 4194304;
  int lr = l & 15, lk8 = l >> 4;
  int sF = (lr >> 1) & 3;                   // frag-read swizzle
  int srow = tid >> 2;                      // staging row 0..63
  int bswz = (tid & 3) ^ ((tid >> 3) & 3);  // staging chunk (A-src & B-dst)
  f32x4 acc[4][2] = {};
  for (int it = 0; it < 8; ++it) {
    int k0 = kbase + it * 64;
    // A: 2 subtiles x 2 rounds each, async gload, source column pre-swizzled
#pragma unroll
    for (int t = 0; t < 2; t++)
#pragma unroll
      for (int rnd = 0; rnd < 2; rnd++) {
        int row = rnd * 64 + srow;
        size_t off = (size_t)row * 1024 + k0 + t * 32 + bswz * 8;
        int lds = t * 4096 + rnd * 2048 + w * 512;
        gload_lds16(Ah + off, &Ahs[lds]);
        gload_lds16(Al + off, &Als[lds]);
      }
    // B: reg-stage f32 -> hi/lo bf16, swizzled ds_write
#pragma unroll
    for (int t = 0; t < 2; t++) {
      const float* g = img + (size_t)(bn + srow) * 1024 + k0 + t * 32 + (tid & 3) * 8;
      f32x4 v0 = *(const f32x4*)g;
      f32x4 v1 = *(const f32x4*)(g + 4);
      s16x8 h, lw;
#pragma unroll
      for (int j = 0; j < 4; j++) {
        unsigned short hb = f2bf(v0[j]);
        h[j] = (short)hb; lw[j] = (short)f2bf(v0[j] - bf2f(hb));
        unsigned short hb1 = f2bf(v1[j]);
        h[j + 4] = (short)hb1; lw[j + 4] = (short)f2bf(v1[j] - bf2f(hb1));
      }
      int byte = t * 4096 + srow * 64 + (bswz << 4);
      *(s16x8*)((char*)Bhs + byte) = h;
      *(s16x8*)((char*)Bls + byte) = lw;
    }
    __syncthreads();
#pragma unroll
    for (int t = 0; t < 2; t++) {
      s16x8 ah[4], al4[4], bh[2], bl[2];
#pragma unroll
      for (int i = 0; i < 4; i++) {
        int byte = t * 8192 + (wm * 64 + i * 16 + lr) * 64 + ((lk8 ^ sF) << 4);
        ah[i] = *(const s16x8*)((const char*)Ahs + byte);
        al4[i] = *(const s16x8*)((const char*)Als + byte);
      }
#pragma unroll
      for (int j = 0; j < 2; j++) {
        int byte = t * 4096 + (wn * 32 + j * 16 + lr) * 64 + ((lk8 ^ sF) << 4);
        bh[j] = *(const s16x8*)((const char*)Bhs + byte);
        bl[j] = *(const s16x8*)((const char*)Bls + byte);
      }
#pragma unroll
      for (int i = 0; i < 4; i++)
#pragma unroll
        for (int j = 0; j < 2; j++) {
          acc[i][j] = __builtin_amdgcn_mfma_f32_16x16x32_bf16(ah[i], bh[j], acc[i][j], 0, 0, 0);
          acc[i][j] = __builtin_amdgcn_mfma_f32_16x16x32_bf16(ah[i], bl[j], acc[i][j], 0, 0, 0);
          acc[i][j] = __builtin_amdgcn_mfma_f32_16x16x32_bf16(al4[i], bh[j], acc[i][j], 0, 0, 0);
        }
    }
    __syncthreads();
  }
  int rh = (l >> 4) * 4;
#pragma unroll
  for (int i = 0; i < 4; i++)
#pragma unroll
    for (int q = 0; q < 4; q++) {
      int gm = wm * 64 + i * 16 + rh + q;
#pragma unroll
      for (int j = 0; j < 2; j++) {
        int gn = bn + wn * 32 + j * 16 + lr;
        S[(size_t)gm * 32768 + gn] = acc[i][j][q];
      }
    }
}

// ---------------- K7: softmax over r (256): sum K-partials, *1/32, f32 -> bf16 [b][l][r] ----------------
__global__ __launch_bounds__(256) void k_softmax(
    const float* __restrict__ S0, unsigned short* __restrict__ P) {
  const float* S1 = S0 + 4194304;
  int w = threadIdx.x >> 6, l = threadIdx.x & 63;
  int row = blockIdx.x * 4 + w;            // row = l*128 + b, 16384 rows
  f32x4 x0 = ((const f32x4*)(S0 + (size_t)row * 256))[l];
  f32x4 x1 = ((const f32x4*)(S1 + (size_t)row * 256))[l];
  f32x4 x;
#pragma unroll
  for (int j = 0; j < 4; j++) x[j] = x0[j] + x1[j];
  float m = fmaxf(fmaxf(x[0], x[1]), fmaxf(x[2], x[3]));
#pragma unroll
  for (int s = 1; s < 64; s <<= 1) m = fmaxf(m, __shfl_xor(m, s, 64));
  f32x4 e;
  float sum = 0.f;
#pragma unroll
  for (int j = 0; j < 4; j++) { e[j] = __expf(x[j] - m); sum += e[j]; }
#pragma unroll
  for (int s = 1; s < 64; s <<= 1) sum += __shfl_xor(sum, s, 64);
  float sc = 0.03125f / sum;
  s16x4 o;
#pragma unroll
  for (int j = 0; j < 4; j++) o[j] = (short)f2bf(e[j] * sc);
  // transpose the (l,b) indexing: write to attenB[b][l][r]
  int bb = row & 127, ll = row >> 7;
  ((s16x4*)(P + ((size_t)bb * 128 + ll) * 256))[l] = o;
}

// ---------------- K9: ctx[b][l][d] = sum_r attenB[b][l][r] * img[b][r][d] ----------------
// TN MFMA; A staged async (source pre-swizzled), B read as f32, converted +
// transposed into LDS via pack-pair reg staging with XOR swizzle.
__global__ __launch_bounds__(256, 3) void k_gemm_ctx(
    const unsigned short* __restrict__ P, const float* __restrict__ img,
    unsigned short* __restrict__ Cp) {
  __shared__ unsigned short As[4096];   // atten [128 l][32 r], src-preswizzled
  __shared__ unsigned short Bs[4096];   // imgT [128 d][32 r], chunk^((d>>1)&3)
  int tid = threadIdx.x, l = tid & 63, w = tid >> 6;
  int wm = w >> 1, wn = w & 1;
  int rid = blockIdx.x;
  int xcd = rid & 7, lid = rid >> 3;
  int b = xcd * 16 + (lid >> 3);
  int d0 = (lid & 7) * 128;
  const unsigned short* Pb = P + (size_t)b * 32768;
  int lr = l & 15, lk8 = l >> 4;
  int sF = (lr >> 1) & 3;
  int u = tid & 15, dc = tid >> 4;
  int bswz = (tid & 3) ^ ((tid >> 3) & 3);
  f32x4 acc[4][4] = {};
  for (int k0 = 0; k0 < 256; k0 += 32) {
    // A: atten rows, linear gload_lds, source column pre-swizzled
#pragma unroll
    for (int rnd = 0; rnd < 2; rnd++) {
      int row = rnd * 64 + (tid >> 2);
      gload_lds16(Pb + (size_t)row * 256 + k0 + bswz * 8, &As[rnd * 2048 + w * 512]);
    }
    // B: transpose-stage img[b][k0+r][d0+d] f32 -> bf16 pairs -> Bs[d][r]
    {
      const float* gsrc = img + ((size_t)(b * 256 + k0 + 2 * u)) * 1024 + d0 + dc * 8;
      f32x4 a0 = *(const f32x4*)gsrc;
      f32x4 a1 = *(const f32x4*)(gsrc + 4);
      f32x4 b0 = *(const f32x4*)(gsrc + 1024);
      f32x4 b1 = *(const f32x4*)(gsrc + 1028);
#pragma unroll
      for (int j = 0; j < 8; j++) {
        float x0 = (j < 4) ? a0[j & 3] : a1[j & 3];
        float x1 = (j < 4) ? b0[j & 3] : b1[j & 3];
        int d = dc * 8 + j;
        unsigned int w32 = (unsigned int)f2bf(x0) | ((unsigned int)f2bf(x1) << 16);
        int byte = d * 64 + ((4 * u) ^ (((d >> 1) & 3) << 4));
        *(unsigned int*)((char*)Bs + byte) = w32;
      }
    }
    __syncthreads();
    s16x8 af[4], bf[4];
#pragma unroll
    for (int i = 0; i < 4; i++) {
      int byte = (wm * 64 + i * 16 + lr) * 64 + ((lk8 ^ sF) << 4);
      af[i] = *(const s16x8*)((const char*)As + byte);
    }
#pragma unroll
    for (int j = 0; j < 4; j++) {
      int n = wn * 64 + j * 16 + lr;
      int byte = n * 64 + ((lk8 ^ sF) << 4);
      bf[j] = *(const s16x8*)((const char*)Bs + byte);
    }
#pragma unroll
    for (int i = 0; i < 4; i++)
#pragma unroll
      for (int j = 0; j < 4; j++)
        acc[i][j] = __builtin_amdgcn_mfma_f32_16x16x32_bf16(af[i], bf[j], acc[i][j], 0, 0, 0);
    __syncthreads();
  }
  int rh = (l >> 4) * 4;
#pragma unroll
  for (int i = 0; i < 4; i++)
#pragma unroll
    for (int q = 0; q < 4; q++) {
      int gm = wm * 64 + i * 16 + rh + q;
#pragma unroll
      for (int j = 0; j < 4; j++) {
        int gn = wn * 64 + j * 16 + lr;
        Cp[((size_t)b * 128 + gm) * 1024 + d0 + gn] = f2bf(acc[i][j][q]);
      }
    }
}

// ---------------- K10: out[m][n] = sum_k ctx[m][k]*Wv[n][k] + bv[n]/32 ----------------
// M=16384, N=1024, K=1024. TN, swizzled LDS, XCD-grouped.
__global__ __launch_bounds__(256, 3) void k_gemm_out(
    const unsigned short* __restrict__ A, const unsigned short* __restrict__ Bm,
    const float* __restrict__ bv, float* __restrict__ Out) {
  __shared__ unsigned short As[4096], Bs[4096];
  int tid = threadIdx.x, l = tid & 63, w = tid >> 6;
  int wm = w >> 1, wn = w & 1;
  int rid = blockIdx.x;
  int xcd = rid & 7, lid = rid >> 3;
  int bm = (xcd * 16 + (lid >> 3)) * 128;
  int bn = (lid & 7) * 128;
  int lr = l & 15, lk8 = l >> 4;
  int sF = (lr >> 1) & 3;
  int swz = ((tid & 3) ^ ((tid >> 3) & 3));   // source-col swizzle for staging
  f32x4 acc[4][4] = {};
  for (int k0 = 0; k0 < 1024; k0 += 32) {
#pragma unroll
    for (int rnd = 0; rnd < 2; rnd++) {
      int row = rnd * 64 + (tid >> 2);
      int lbase = rnd * 2048 + w * 512;
      gload_lds16(A + (size_t)(bm + row) * 1024 + k0 + swz * 8, &As[lbase]);
      gload_lds16(Bm + (size_t)(bn + row) * 1024 + k0 + swz * 8, &Bs[lbase]);
    }
    __syncthreads();
    s16x8 af[4], bf[4];
#pragma unroll
    for (int i = 0; i < 4; i++) {
      int byte = (wm * 64 + i * 16 + lr) * 64 + ((lk8 ^ sF) << 4);
      af[i] = *(const s16x8*)((const char*)As + byte);
    }
#pragma unroll
    for (int i = 0; i < 4; i++) {
      int byte = (wn * 64 + i * 16 + lr) * 64 + ((lk8 ^ sF) << 4);
      bf[i] = *(const s16x8*)((const char*)Bs + byte);
    }
#pragma unroll
    for (int i = 0; i < 4; i++)
#pragma unroll
      for (int j = 0; j < 4; j++)
        acc[i][j] = __builtin_amdgcn_mfma_f32_16x16x32_bf16(af[i], bf[j], acc[i][j], 0, 0, 0);
    __syncthreads();
  }
  int rh = (l >> 4) * 4;
#pragma unroll
  for (int i = 0; i < 4; i++)
#pragma unroll
    for (int q = 0; q < 4; q++) {
      int gm = bm + wm * 64 + i * 16 + rh + q;
#pragma unroll
      for (int j = 0; j < 4; j++) {
        int gn = bn + wn * 64 + j * 16 + lr;
        Out[(size_t)gm * 1024 + gn] = acc[i][j][q] + 0.03125f * bv[gn];
      }
    }
}

extern "C" void kernel_launch(void* const* d_in, const int* in_sizes, int n_in,
                              void* d_out, int out_size, void* d_ws, size_t ws_size,
                              hipStream_t stream) {
  const float* cap = (const float*)d_in[0];
  const float* img = (const float*)d_in[1];
  const float* Wq  = (const float*)d_in[2];
  const float* bq  = (const float*)d_in[3];
  const float* Wk  = (const float*)d_in[4];
  // d_in[5] = bk: constant across r -> cancels in softmax. Unused.
  const float* Wv  = (const float*)d_in[6];
  const float* bv  = (const float*)d_in[7];
  float* out = (float*)d_out;

  char* ws = (char*)d_ws;
  if (ws_size < 78643200ull) return;  // fail loudly (output stays poisoned)
  float*          scores = (float*)(ws);                     // 32 MB (2 K-halves)
  unsigned short* atten  = (unsigned short*)(ws + 33554432); //  8 MB
  unsigned short* ctx    = (unsigned short*)(ws + 41943040); // 32 MB
  float*          Qb     = (float*)(ws + 75497472);          // 512 KB
  unsigned short* QWh    = (unsigned short*)(ws + 76021760); // 256 KB
  unsigned short* QWl    = (unsigned short*)(ws + 76283904); // 256 KB
  unsigned short* Wvh    = (unsigned short*)(ws + 76546048); //   2 MB

  k_convert_hi<<<1024, 256, 0, stream>>>(Wv, Wvh, 1048576 / 4);
  // Q = cap @ Wq^T + bq  (f32)
  k_gemm_f32_tn<<<dim3(4, 32), 256, 0, stream>>>(cap, Wq, bq, Qb, 128, 1024, 1024);
  // QW = Q @ Wk  (f32 -> bf16 hi/lo)
  k_gemm_f32_nn_split<<<dim3(4, 32), 256, 0, stream>>>(Qb, Wk, QWh, QWl, 128, 1024, 1024);
  // score partials = QW @ img^T  (3-pass split bf16, BK=64 dual subtiles)
  k_gemm_scores<<<1024, 256, 0, stream>>>(QWh, QWl, img, scores);
  // atten[b][l][r] = softmax(sum of partials) / 32  (bf16)
  k_softmax<<<4096, 256, 0, stream>>>(scores, atten);
  // ctx[b][l][d] = atten[b] @ img[b]  (bf16, swizzled staging)
  k_gemm_ctx<<<1024, 256, 0, stream>>>(atten, img, ctx);
  // out = ctx @ Wv^T + bv/32
  k_gemm_out<<<1024, 256, 0, stream>>>(ctx, Wvh, bv, out);
}